// Round 11
// baseline (197.499 us; speedup 1.0000x reference)
//
#include <hip/hip_runtime.h>

#define NTAG 64
#define TLEN 512
#define HALF (TLEN / 2)
#define START_TAG 62
#define STOP_TAG 63
#define CHUNK 32          // timesteps staged per LDS buffer

typedef float v2f __attribute__((ext_vector_type(2)));

// One workgroup (128 thr = 2 waves) per batch. wave0: fwd consumes w_0..255;
// wave1: bwd seeds z=S*w_511, steps w_510..256, one bare E^T matvec.
// Linear domain; exact pow2 renorm every step (zero-guarded, ref = tag 0).
//
// Round-11 = round-8 skeleton + round-10 state format:
//  - emissions exp'd and staged in LDS chunks of 32 steps, double-buffered,
//    global float4 loads a full chunk ahead (ONE vmcnt wait per 32 steps —
//    round 10 proved per-step VMEM loads expose ~500 cyc/step of latency
//    because the compiler emits conservative per-step waitcnts)
//  - state = packed bf16 in LDS: 8 wave-uniform ds_read_b128 (HW broadcast,
//    conflict-free) deliver all 64 tags; unpack is exact bit ops
//    (lo = u<<16, hi = u&0xffff0000); dot via v_pk_fma_f32. Halves the
//    DS-pipe demand vs the f32 state (rounds 5/8 were DS-pipe-bound:
//    4 waves/CU x ~200 cyc/step demand ≈ 670-730 measured).
__global__ __launch_bounds__(128) void crf_fwd_bwd(
    const float* __restrict__ emis,   // [B, T, L]
    const float* __restrict__ trans,  // [L, L]  trans[next, prev]
    float* __restrict__ out)          // [B]
{
    const int b    = blockIdx.x;
    const int tid  = threadIdx.x;
    const int lane = tid & 63;
    const int w    = tid >> 6;  // 0 = fwd, 1 = bwd

    __shared__ float lds[2 * 2 * CHUNK * NTAG];            // staged w = exp(emis), 32 KB
    __shared__ __align__(16) unsigned short xst[2][NTAG];  // packed bf16 state per wave
    __shared__ float shv[2][NTAG];
    unsigned short* xs = xst[w];

    const float L2E = 1.4426950408889634f;
    const float LN2 = 0.6931471805599453f;

    // E = exp(trans) rows in f32 VGPR pairs. fwd: E[lane,k]; bwd: E[k,lane].
    // Masked entries (-10000) flush to exactly 0.
    v2f E2[NTAG / 2];
    #pragma unroll
    for (int k2 = 0; k2 < NTAG / 2; ++k2) {
        float e0, e1;
        if (w == 0) { e0 = trans[lane * NTAG + 2 * k2];   e1 = trans[lane * NTAG + 2 * k2 + 1]; }
        else        { e0 = trans[(2 * k2) * NTAG + lane]; e1 = trans[(2 * k2 + 1) * NTAG + lane]; }
        v2f p; p.x = exp2f(e0 * L2E); p.y = exp2f(e1 * L2E);
        E2[k2] = p;
    }

    const float* eb = emis + (size_t)b * TLEN * NTAG;

    // ---- chunk staging (round 8): 8 float4/lane per 32-step chunk ----
    float4 r0, r1, r2, r3, r4, r5, r6, r7;
    #define LOAD_CHUNK(baseT)                                        \
        do {                                                         \
            const float4* gp = (const float4*)(eb + (baseT) * NTAG); \
            r0 = gp[0 * 64 + lane]; r1 = gp[1 * 64 + lane];          \
            r2 = gp[2 * 64 + lane]; r3 = gp[3 * 64 + lane];          \
            r4 = gp[4 * 64 + lane]; r5 = gp[5 * 64 + lane];          \
            r6 = gp[6 * 64 + lane]; r7 = gp[7 * 64 + lane];          \
        } while (0)
    #define EXP4(v) make_float4(exp2f((v).x * L2E), exp2f((v).y * L2E), \
                                exp2f((v).z * L2E), exp2f((v).w * L2E))
    #define STORE_CHUNK_EXP(bufp)                                    \
        do {                                                         \
            float4* b4 = (float4*)(bufp);                            \
            b4[0 * 64 + lane] = EXP4(r0); b4[1 * 64 + lane] = EXP4(r1); \
            b4[2 * 64 + lane] = EXP4(r2); b4[3 * 64 + lane] = EXP4(r3); \
            b4[4 * 64 + lane] = EXP4(r4); b4[5 * 64 + lane] = EXP4(r5); \
            b4[6 * 64 + lane] = EXP4(r6); b4[7 * 64 + lane] = EXP4(r7); \
        } while (0)

    // ---- bf16-packed state matvec (round 10) ----
    // unpack one u32 (2 bf16 tags, little-endian: .x low half = even tag)
    #define UPK_FMA(u, j, acc)                                       \
        do { v2f xp_;                                                \
             xp_.x = __uint_as_float((u) << 16);                     \
             xp_.y = __uint_as_float((u) & 0xffff0000u);             \
             acc = __builtin_elementwise_fma(xp_, E2[j], acc);       \
        } while (0)

    // 8 wave-uniform ds_read_b128 -> whole 64-tag bf16 state (broadcast,
    // conflict-free); 32 packed fma. d_ from tag0's exponent, zero-guarded.
    #define MATVEC_REF(ssum, d_)                                     \
        do {                                                         \
            const uint4* xq_ = (const uint4*)xs;                     \
            uint4 U0 = xq_[0], U1 = xq_[1], U2 = xq_[2], U3 = xq_[3];\
            uint4 U4 = xq_[4], U5 = xq_[5], U6 = xq_[6], U7 = xq_[7];\
            int ef_ = (int)((U0.x >> 7) & 0xffu);                    \
            d_ = (ef_ == 0) ? 0 : ef_ - 127;                         \
            v2f a0={0.f,0.f}, a1={0.f,0.f}, a2={0.f,0.f}, a3={0.f,0.f};\
            UPK_FMA(U0.x,  0, a0); UPK_FMA(U0.y,  1, a1);            \
            UPK_FMA(U0.z,  2, a2); UPK_FMA(U0.w,  3, a3);            \
            UPK_FMA(U1.x,  4, a0); UPK_FMA(U1.y,  5, a1);            \
            UPK_FMA(U1.z,  6, a2); UPK_FMA(U1.w,  7, a3);            \
            UPK_FMA(U2.x,  8, a0); UPK_FMA(U2.y,  9, a1);            \
            UPK_FMA(U2.z, 10, a2); UPK_FMA(U2.w, 11, a3);            \
            UPK_FMA(U3.x, 12, a0); UPK_FMA(U3.y, 13, a1);            \
            UPK_FMA(U3.z, 14, a2); UPK_FMA(U3.w, 15, a3);            \
            UPK_FMA(U4.x, 16, a0); UPK_FMA(U4.y, 17, a1);            \
            UPK_FMA(U4.z, 18, a2); UPK_FMA(U4.w, 19, a3);            \
            UPK_FMA(U5.x, 20, a0); UPK_FMA(U5.y, 21, a1);            \
            UPK_FMA(U5.z, 22, a2); UPK_FMA(U5.w, 23, a3);            \
            UPK_FMA(U6.x, 24, a0); UPK_FMA(U6.y, 25, a1);            \
            UPK_FMA(U6.z, 26, a2); UPK_FMA(U6.w, 27, a3);            \
            UPK_FMA(U7.x, 28, a0); UPK_FMA(U7.y, 29, a1);            \
            UPK_FMA(U7.z, 30, a2); UPK_FMA(U7.w, 31, a3);            \
            v2f s_ = (a0 + a1) + (a2 + a3);                          \
            ssum = s_.x + s_.y;                                      \
        } while (0)

    // f32 -> bf16 (round-to-nearest-ish) state write; 2-way alias = free
    #define WRITE_STATE(v)                                           \
        do { unsigned bx_ = __float_as_uint((float)(v));             \
             xs[lane] = (unsigned short)((bx_ + 0x8000u) >> 16);     \
        } while (0)

    // x_new = (E . x) * em * 2^-d ; em*rs overlaps the dot tree
    #define STEP(buf, s)                                             \
        do {                                                         \
            float em_ = (buf)[(s) * NTAG + lane];                    \
            float ssum_; int d_;                                     \
            MATVEC_REF(ssum_, d_);                                   \
            off += d_;                                               \
            float rs_ = __uint_as_float((unsigned)(127 - d_) << 23); \
            x = ssum_ * (em_ * rs_);                                 \
            WRITE_STATE(x);                                          \
        } while (0)

    float x   = 0.0f;
    int   off = 0;   // accumulated power-of-2 offset (exact, lane-uniform)

    if (w == 0) {
        WRITE_STATE(lane == START_TAG ? 1.0f : 0.0f);   // a_0 = indicator

        LOAD_CHUNK(0);
        #pragma clang loop unroll(disable)
        for (int ci = 0; ci < 8; ++ci) {
            float* buf = &lds[(ci & 1) * (CHUNK * NTAG)];
            STORE_CHUNK_EXP(buf);
            if (ci < 7) LOAD_CHUNK((ci + 1) * CHUNK);   // in flight ~32 steps

            #pragma clang loop unroll_count(4)
            for (int s = 0; s < CHUNK; ++s) STEP(buf, s);  // w_0..w_255
        }
        // x = alpha_255 (linear f32, scaled by 2^off)
    } else {
        float Sv = exp2f(trans[STOP_TAG * NTAG + lane] * L2E);  // exp(trans[STOP,:])

        LOAD_CHUNK(HALF + 7 * CHUNK);
        #pragma clang loop unroll(disable)
        for (int i = 0; i < 8; ++i) {
            float* buf = &lds[(2 + (i & 1)) * (CHUNK * NTAG)];
            STORE_CHUNK_EXP(buf);
            if (i < 7) LOAD_CHUNK(HALF + (6 - i) * CHUNK);

            int s0 = CHUNK - 1;
            if (i == 0) {
                // seed z_511 = S * w_511 (w_511 staged just above)
                WRITE_STATE(Sv * buf[(CHUNK - 1) * NTAG + lane]);
                s0 = CHUNK - 2;
            }
            #pragma clang loop unroll_count(4)
            for (int s = s0; s >= 0; --s) STEP(buf, s);    // w_510..w_256
        }
        // bare matvec: beta_255 = E^T z_256 (renorm folded, exact)
        {
            float ssum_; int d_;
            MATVEC_REF(ssum_, d_);
            off += d_;
            x = ssum_ * __uint_as_float((unsigned)(127 - d_) << 23);
        }
    }

    // merge the half-chains in log2 domain
    shv[w][lane] = log2f(x) + (float)off;   // -inf for masked tags, safe
    __syncthreads();

    if (w == 0) {
        float v = shv[0][lane] + shv[1][lane];
        float m = v;
        #pragma unroll
        for (int d = 1; d < 64; d <<= 1) m = fmaxf(m, __shfl_xor(m, d, 64));
        float e = exp2f(v - m);
        #pragma unroll
        for (int d = 1; d < 64; d <<= 1) e += __shfl_xor(e, d, 64);
        if (lane == 0) out[b] = LN2 * (m + log2f(e));
    }
}

extern "C" void kernel_launch(void* const* d_in, const int* in_sizes, int n_in,
                              void* d_out, int out_size, void* d_ws, size_t ws_size,
                              hipStream_t stream) {
    const float* emis  = (const float*)d_in[0];   // [512, 512, 64] f32
    const float* trans = (const float*)d_in[1];   // [64, 64] f32
    float* out = (float*)d_out;                   // [512] f32
    (void)in_sizes; (void)n_in; (void)out_size; (void)d_ws; (void)ws_size;
    crf_fwd_bwd<<<512, 128, 0, stream>>>(emis, trans, out);
}

// Round 12
// 156.210 us; speedup vs baseline: 1.2643x; 1.2643x over previous
//
#include <hip/hip_runtime.h>

#define NTAG 64
#define TLEN 512
#define HALF (TLEN / 2)
#define START_TAG 62
#define STOP_TAG 63
#define CHUNK 32          // timesteps staged per LDS buffer

typedef float v2f __attribute__((ext_vector_type(2)));

// One workgroup (128 thr = 2 waves) per batch. wave0: fwd consumes w_0..255;
// wave1: bwd seeds z=S*w_511, steps w_510..256, one bare E^T matvec.
// Linear domain; exact pow2 renorm every step (zero-guarded, ref = tag 0).
//
// Round-12 = round-8 champion (71.5us) with ONE change: the 64 scalar fma
// of the matvec become 32 v2f fma whose operands are the ds_read_b128 quads
// used AS-IS (consecutive VGPRs = natural v_pk_fma_f32 pairs, zero unpack).
// Round-11 postmortem: bf16 packing inflated VALU 221->478 cyc/step (unpack
// bit-ops + pair-forming movs) — packed math only pays with naturally
// aligned operands, which f32 quads are. Worst case this scalarizes back
// to round 8's exact instruction stream.
__global__ __launch_bounds__(128) void crf_fwd_bwd(
    const float* __restrict__ emis,   // [B, T, L]
    const float* __restrict__ trans,  // [L, L]  trans[next, prev]
    float* __restrict__ out)          // [B]
{
    const int b    = blockIdx.x;
    const int tid  = threadIdx.x;
    const int lane = tid & 63;
    const int w    = tid >> 6;  // 0 = fwd, 1 = bwd

    __shared__ float lds[2 * 2 * CHUNK * NTAG];      // staged w = exp(emis), 32 KB
    __shared__ __align__(16) float xst[2][NTAG];     // f32 state per wave
    __shared__ float shv[2][NTAG];
    float* xs = xst[w];

    const float L2E = 1.4426950408889634f;
    const float LN2 = 0.6931471805599453f;

    // E = exp(trans) as 32 v2f pairs. fwd: E[lane,k]; bwd: E[k,lane].
    // Masked entries (-10000) flush to exactly 0.
    v2f E2[NTAG / 2];
    #pragma unroll
    for (int k2 = 0; k2 < NTAG / 2; ++k2) {
        float e0, e1;
        if (w == 0) { e0 = trans[lane * NTAG + 2 * k2];   e1 = trans[lane * NTAG + 2 * k2 + 1]; }
        else        { e0 = trans[(2 * k2) * NTAG + lane]; e1 = trans[(2 * k2 + 1) * NTAG + lane]; }
        v2f p; p.x = exp2f(e0 * L2E); p.y = exp2f(e1 * L2E);
        E2[k2] = p;
    }

    const float* eb = emis + (size_t)b * TLEN * NTAG;

    // ---- chunk staging (round 8): 8 float4/lane per 32-step chunk ----
    float4 r0, r1, r2, r3, r4, r5, r6, r7;
    #define LOAD_CHUNK(baseT)                                        \
        do {                                                         \
            const float4* gp = (const float4*)(eb + (baseT) * NTAG); \
            r0 = gp[0 * 64 + lane]; r1 = gp[1 * 64 + lane];          \
            r2 = gp[2 * 64 + lane]; r3 = gp[3 * 64 + lane];          \
            r4 = gp[4 * 64 + lane]; r5 = gp[5 * 64 + lane];          \
            r6 = gp[6 * 64 + lane]; r7 = gp[7 * 64 + lane];          \
        } while (0)
    #define EXP4(v) make_float4(exp2f((v).x * L2E), exp2f((v).y * L2E), \
                                exp2f((v).z * L2E), exp2f((v).w * L2E))
    #define STORE_CHUNK_EXP(bufp)                                    \
        do {                                                         \
            float4* b4 = (float4*)(bufp);                            \
            b4[0 * 64 + lane] = EXP4(r0); b4[1 * 64 + lane] = EXP4(r1); \
            b4[2 * 64 + lane] = EXP4(r2); b4[3 * 64 + lane] = EXP4(r3); \
            b4[4 * 64 + lane] = EXP4(r4); b4[5 * 64 + lane] = EXP4(r5); \
            b4[6 * 64 + lane] = EXP4(r6); b4[7 * 64 + lane] = EXP4(r7); \
        } while (0)

    // one float4 quad = two natural v2f pairs; fma against E2 pairs
    #define QFMA(xv, j, accA, accB)                                  \
        do { v2f lo_, hi_;                                           \
             lo_.x = (xv).x; lo_.y = (xv).y;                         \
             hi_.x = (xv).z; hi_.y = (xv).w;                         \
             accA = __builtin_elementwise_fma(lo_, E2[2*(j)],   accA); \
             accB = __builtin_elementwise_fma(hi_, E2[2*(j)+1], accB); \
        } while (0)

    // 16 wave-uniform ds_read_b128 (HW broadcast, conflict-free) + 32 v2f
    // fma into 8 v2f accumulators. d_ from tag0's exponent, zero-guarded
    // (fwd seed has tag0 == 0 -> exponent field 0 -> no rescale).
    #define MATVEC_REF(ssum, d_)                                     \
        do {                                                         \
            const float4* xq_ = (const float4*)xs;                   \
            float4 xv_[16];                                          \
            _Pragma("unroll")                                        \
            for (int j = 0; j < 16; ++j) xv_[j] = xq_[j];            \
            int ef_ = (int)((__float_as_uint(xv_[0].x) >> 23) & 0xffu); \
            d_ = (ef_ == 0) ? 0 : ef_ - 127;                         \
            v2f a0={0.f,0.f}, a1={0.f,0.f}, a2={0.f,0.f}, a3={0.f,0.f};\
            v2f a4={0.f,0.f}, a5={0.f,0.f}, a6={0.f,0.f}, a7={0.f,0.f};\
            QFMA(xv_[0],  0, a0, a1); QFMA(xv_[1],  1, a2, a3);      \
            QFMA(xv_[2],  2, a4, a5); QFMA(xv_[3],  3, a6, a7);      \
            QFMA(xv_[4],  4, a0, a1); QFMA(xv_[5],  5, a2, a3);      \
            QFMA(xv_[6],  6, a4, a5); QFMA(xv_[7],  7, a6, a7);      \
            QFMA(xv_[8],  8, a0, a1); QFMA(xv_[9],  9, a2, a3);      \
            QFMA(xv_[10], 10, a4, a5); QFMA(xv_[11], 11, a6, a7);    \
            QFMA(xv_[12], 12, a0, a1); QFMA(xv_[13], 13, a2, a3);    \
            QFMA(xv_[14], 14, a4, a5); QFMA(xv_[15], 15, a6, a7);    \
            v2f s_ = ((a0 + a1) + (a2 + a3)) + ((a4 + a5) + (a6 + a7)); \
            ssum = s_.x + s_.y;                                      \
        } while (0)

    #define WRITE_STATE(v) (xs[lane] = (v))

    // x_new = (E . x) * em * 2^-d ; em*rs overlaps the dot tree
    #define STEP(buf, s)                                             \
        do {                                                         \
            float em_ = (buf)[(s) * NTAG + lane];                    \
            float ssum_; int d_;                                     \
            MATVEC_REF(ssum_, d_);                                   \
            off += d_;                                               \
            float rs_ = __uint_as_float((unsigned)(127 - d_) << 23); \
            x = ssum_ * (em_ * rs_);                                 \
            WRITE_STATE(x);                                          \
        } while (0)

    float x   = 0.0f;
    int   off = 0;   // accumulated power-of-2 offset (exact, lane-uniform)

    if (w == 0) {
        WRITE_STATE(lane == START_TAG ? 1.0f : 0.0f);   // a_0 = indicator

        LOAD_CHUNK(0);
        #pragma clang loop unroll(disable)
        for (int ci = 0; ci < 8; ++ci) {
            float* buf = &lds[(ci & 1) * (CHUNK * NTAG)];
            STORE_CHUNK_EXP(buf);
            if (ci < 7) LOAD_CHUNK((ci + 1) * CHUNK);   // in flight ~32 steps

            #pragma clang loop unroll_count(4)
            for (int s = 0; s < CHUNK; ++s) STEP(buf, s);  // w_0..w_255
        }
        // x = alpha_255 (linear f32, scaled by 2^off)
    } else {
        float Sv = exp2f(trans[STOP_TAG * NTAG + lane] * L2E);  // exp(trans[STOP,:])

        LOAD_CHUNK(HALF + 7 * CHUNK);
        #pragma clang loop unroll(disable)
        for (int i = 0; i < 8; ++i) {
            float* buf = &lds[(2 + (i & 1)) * (CHUNK * NTAG)];
            STORE_CHUNK_EXP(buf);
            if (i < 7) LOAD_CHUNK(HALF + (6 - i) * CHUNK);

            int s0 = CHUNK - 1;
            if (i == 0) {
                // seed z_511 = S * w_511 (w_511 staged just above)
                WRITE_STATE(Sv * buf[(CHUNK - 1) * NTAG + lane]);
                s0 = CHUNK - 2;
            }
            #pragma clang loop unroll_count(4)
            for (int s = s0; s >= 0; --s) STEP(buf, s);    // w_510..w_256
        }
        // bare matvec: beta_255 = E^T z_256 (renorm folded, exact)
        {
            float ssum_; int d_;
            MATVEC_REF(ssum_, d_);
            off += d_;
            x = ssum_ * __uint_as_float((unsigned)(127 - d_) << 23);
        }
    }

    // merge the half-chains in log2 domain
    shv[w][lane] = log2f(x) + (float)off;   // -inf for masked tags, safe
    __syncthreads();

    if (w == 0) {
        float v = shv[0][lane] + shv[1][lane];
        float m = v;
        #pragma unroll
        for (int d = 1; d < 64; d <<= 1) m = fmaxf(m, __shfl_xor(m, d, 64));
        float e = exp2f(v - m);
        #pragma unroll
        for (int d = 1; d < 64; d <<= 1) e += __shfl_xor(e, d, 64);
        if (lane == 0) out[b] = LN2 * (m + log2f(e));
    }
}

extern "C" void kernel_launch(void* const* d_in, const int* in_sizes, int n_in,
                              void* d_out, int out_size, void* d_ws, size_t ws_size,
                              hipStream_t stream) {
    const float* emis  = (const float*)d_in[0];   // [512, 512, 64] f32
    const float* trans = (const float*)d_in[1];   // [64, 64] f32
    float* out = (float*)d_out;                   // [512] f32
    (void)in_sizes; (void)n_in; (void)out_size; (void)d_ws; (void)ws_size;
    crf_fwd_bwd<<<512, 128, 0, stream>>>(emis, trans, out);
}